// Round 1
// baseline (1869.421 us; speedup 1.0000x reference)
//
#include <hip/hip_runtime.h>
#include <hip/hip_bf16.h>
#include <cstdint>

#define NTOK 4096
#define DMODEL 2048
#define NEXP 8
#define HR 1408
#define HSHARED 2816
#define MAXTILES 136   // sum ceil(c_e/64) <= 8192/64 + 8

typedef __attribute__((ext_vector_type(8))) short bf16x8;
typedef __attribute__((ext_vector_type(4))) float f32x4;

__device__ inline unsigned short f2b(float f) {
    unsigned u = __float_as_uint(f);
    u += 0x7fffu + ((u >> 16) & 1u);   // RNE
    return (unsigned short)(u >> 16);
}
__device__ inline unsigned pack2(float a, float b) {
    return (unsigned)f2b(a) | ((unsigned)f2b(b) << 16);
}

// ---------------- Router: logits -> softmax -> top2 -> counts ----------------
__global__ __launch_bounds__(256) void k_router(const float* __restrict__ x,
                                                const float* __restrict__ rw,
                                                int* __restrict__ topi,
                                                float* __restrict__ topw,
                                                int* __restrict__ counts) {
    int gw = (blockIdx.x * 256 + threadIdx.x) >> 6;   // one wave per token
    int lane = threadIdx.x & 63;
    if (gw >= NTOK) return;
    const float* xr = x + (size_t)gw * DMODEL;
    float s[NEXP] = {0.f,0.f,0.f,0.f,0.f,0.f,0.f,0.f};
    for (int d = lane; d < DMODEL; d += 64) {
        float xv = xr[d];
#pragma unroll
        for (int e = 0; e < NEXP; e++) s[e] = fmaf(xv, rw[e * DMODEL + d], s[e]);
    }
#pragma unroll
    for (int e = 0; e < NEXP; e++)
        for (int o = 32; o > 0; o >>= 1) s[e] += __shfl_xor(s[e], o, 64);
    if (lane == 0) {
        // top-2 on logits (softmax is monotonic); lowest index wins ties like lax.top_k
        int i1 = 0;
#pragma unroll
        for (int e = 1; e < NEXP; e++) if (s[e] > s[i1]) i1 = e;
        int i2 = (i1 == 0) ? 1 : 0;
#pragma unroll
        for (int e = 0; e < NEXP; e++) if (e != i1 && s[e] > s[i2]) i2 = e;
        float mx = s[0];
#pragma unroll
        for (int e = 1; e < NEXP; e++) mx = fmaxf(mx, s[e]);
        float den = 0.f, ex[NEXP];
#pragma unroll
        for (int e = 0; e < NEXP; e++) { ex[e] = __expf(s[e] - mx); den += ex[e]; }
        float v1 = ex[i1] / den, v2 = ex[i2] / den;
        float inv = 1.f / (v1 + v2 + 1e-20f);
        topi[2 * gw] = i1; topi[2 * gw + 1] = i2;
        topw[2 * gw] = v1 * inv; topw[2 * gw + 1] = v2 * inv;
        atomicAdd(&counts[i1], 1); atomicAdd(&counts[i2], 1);
    }
}

// ------------- Scan: offsets, cursors, tile table (serial, tiny) -------------
__global__ void k_scan(int* counts, int* offsets, int* cursors, int* ntiles,
                       int* tile_e, int* tile_r) {
    if (threadIdx.x == 0 && blockIdx.x == 0) {
        int off = 0, nt = 0;
        for (int e = 0; e < NEXP; e++) {
            offsets[e] = off; cursors[e] = off;
            int c = counts[e];
            for (int r = 0; r < c; r += 64) { tile_e[nt] = e; tile_r[nt] = r; nt++; }
            off += c;
        }
        ntiles[0] = nt;
    }
}

// ---------------- Fill gathered assignment lists ----------------
__global__ __launch_bounds__(256) void k_fill(const int* __restrict__ topi,
                                              const float* __restrict__ topw,
                                              int* cursors, int* at, float* aw) {
    int t = blockIdx.x * 256 + threadIdx.x;
    if (t >= NTOK) return;
#pragma unroll
    for (int k = 0; k < 2; k++) {
        int e = topi[2 * t + k];
        int pos = atomicAdd(&cursors[e], 1);
        at[pos] = t; aw[pos] = topw[2 * t + k];
    }
}

// ---------------- Stage 1: fused gate/up GEMM + silu*mul -> bf16 h ----------
// A = x rows (gathered or identity), fp32 [*,D]; B = Wg/Wu [D,Hld] fp32.
// 64x64 block tile, 4 waves 2x2, mfma 16x16x32 bf16, K=DMODEL.
template <bool GATHERED>
__global__ __launch_bounds__(256) void k_gateup(
    const float* __restrict__ x, const float* __restrict__ Wg,
    const float* __restrict__ Wu, int Hld,
    const int* __restrict__ tile_e, const int* __restrict__ tile_r,
    const int* __restrict__ offsets, const int* __restrict__ counts,
    const int* __restrict__ ntiles, const int* __restrict__ at,
    unsigned short* __restrict__ hout) {
    int m0, mcnt;
    const float* wgp = Wg;
    const float* wup = Wu;
    if (GATHERED) {
        if ((int)blockIdx.x >= ntiles[0]) return;
        int e = tile_e[blockIdx.x], ro = tile_r[blockIdx.x];
        m0 = offsets[e] + ro;
        mcnt = counts[e] - ro; if (mcnt > 64) mcnt = 64;
        size_t wofs = (size_t)e * DMODEL * Hld;
        wgp += wofs; wup += wofs;
    } else { m0 = blockIdx.x * 64; mcnt = 64; }
    int n0 = blockIdx.y * 64;

    __shared__ unsigned short As[64][48];
    __shared__ unsigned short Bgs[64][48];
    __shared__ unsigned short Bus[64][48];

    int tid = threadIdx.x;
    // A staging: row ai, 8 consecutive k
    int ai = tid >> 2, ak = (tid & 3) << 3;
    int arowi = m0 + (ai < mcnt ? ai : (mcnt - 1));
    const float* arow = x + (size_t)(GATHERED ? at[arowi] : arowi) * DMODEL;
    // B staging: col bn, pairs of k
    int bn = tid >> 2, bk = (tid & 3) << 1;
    const float* bcolg = wgp + (size_t)n0 + bn;
    const float* bcolu = wup + (size_t)n0 + bn;

    int lane = tid & 63, wv = tid >> 6;
    int wm = (wv & 1) << 5, wn = (wv >> 1) << 5;
    int fr = lane & 15, fk = (lane >> 4) << 3;

    f32x4 accg[2][2] = {};
    f32x4 accu[2][2] = {};

    for (int k0 = 0; k0 < DMODEL; k0 += 32) {
        __syncthreads();
        float4 a0 = *(const float4*)(arow + k0 + ak);
        float4 a1 = *(const float4*)(arow + k0 + ak + 4);
        uint4 av; av.x = pack2(a0.x, a0.y); av.y = pack2(a0.z, a0.w);
        av.z = pack2(a1.x, a1.y); av.w = pack2(a1.z, a1.w);
        *(uint4*)&As[ai][ak] = av;
#pragma unroll
        for (int j = 0; j < 4; j++) {
            int kk = bk + (j << 3);
            size_t o0 = (size_t)(k0 + kk) * Hld;
            float g0 = bcolg[o0], g1 = bcolg[o0 + Hld];
            float u0 = bcolu[o0], u1 = bcolu[o0 + Hld];
            *(unsigned*)&Bgs[bn][kk] = pack2(g0, g1);
            *(unsigned*)&Bus[bn][kk] = pack2(u0, u1);
        }
        __syncthreads();
        bf16x8 af[2], bg[2], bu[2];
#pragma unroll
        for (int t = 0; t < 2; t++) {
            af[t] = *(bf16x8*)&As[wm + t * 16 + fr][fk];
            bg[t] = *(bf16x8*)&Bgs[wn + t * 16 + fr][fk];
            bu[t] = *(bf16x8*)&Bus[wn + t * 16 + fr][fk];
        }
#pragma unroll
        for (int tm = 0; tm < 2; tm++)
#pragma unroll
            for (int tn = 0; tn < 2; tn++) {
                accg[tm][tn] = __builtin_amdgcn_mfma_f32_16x16x32_bf16(af[tm], bg[tn], accg[tm][tn], 0, 0, 0);
                accu[tm][tn] = __builtin_amdgcn_mfma_f32_16x16x32_bf16(af[tm], bu[tn], accu[tm][tn], 0, 0, 0);
            }
    }
    // epilogue: h = silu(g)*u, bf16  (C/D: col=lane&15, row=quad*4+reg)
    int quad = (lane >> 4) << 2;
#pragma unroll
    for (int tm = 0; tm < 2; tm++)
#pragma unroll
        for (int r = 0; r < 4; r++) {
            int row = wm + tm * 16 + quad + r;
            if (row < mcnt) {
#pragma unroll
                for (int tn = 0; tn < 2; tn++) {
                    float g = accg[tm][tn][r], u = accu[tm][tn][r];
                    float hv = (g / (1.f + __expf(-g))) * u;
                    hout[(size_t)(m0 + row) * Hld + n0 + wn + tn * 16 + fr] = f2b(hv);
                }
            }
        }
}

// ---------------- Stage 2: down GEMM, weighted atomic scatter-add ------------
// A = h rows bf16 [*,Hld]; B = Wd [Hld,D] fp32; out[token] += w * (A@B)
template <bool GATHERED>
__global__ __launch_bounds__(256) void k_down(
    const unsigned short* __restrict__ h, const float* __restrict__ Wd, int Hld,
    const int* __restrict__ tile_e, const int* __restrict__ tile_r,
    const int* __restrict__ offsets, const int* __restrict__ counts,
    const int* __restrict__ ntiles, const int* __restrict__ at,
    const float* __restrict__ aw, float* __restrict__ out) {
    int m0, mcnt;
    const float* wdp = Wd;
    if (GATHERED) {
        if ((int)blockIdx.x >= ntiles[0]) return;
        int e = tile_e[blockIdx.x], ro = tile_r[blockIdx.x];
        m0 = offsets[e] + ro;
        mcnt = counts[e] - ro; if (mcnt > 64) mcnt = 64;
        wdp += (size_t)e * Hld * DMODEL;
    } else { m0 = blockIdx.x * 64; mcnt = 64; }
    int n0 = blockIdx.y * 64;

    __shared__ unsigned short As[64][48];
    __shared__ unsigned short Bs[64][48];

    int tid = threadIdx.x;
    int ai = tid >> 2, ak = (tid & 3) << 3;
    const unsigned short* arow = h + (size_t)(m0 + (ai < mcnt ? ai : (mcnt - 1))) * Hld;
    int bn = tid >> 2, bk = (tid & 3) << 1;
    const float* bcol = wdp + (size_t)n0 + bn;

    int lane = tid & 63, wv = tid >> 6;
    int wm = (wv & 1) << 5, wn = (wv >> 1) << 5;
    int fr = lane & 15, fk = (lane >> 4) << 3;

    f32x4 acc[2][2] = {};

    for (int k0 = 0; k0 < Hld; k0 += 32) {
        __syncthreads();
        *(uint4*)&As[ai][ak] = *(const uint4*)(arow + k0 + ak);
#pragma unroll
        for (int j = 0; j < 4; j++) {
            int kk = bk + (j << 3);
            size_t o0 = (size_t)(k0 + kk) * DMODEL;
            float b0 = bcol[o0], b1 = bcol[o0 + DMODEL];
            *(unsigned*)&Bs[bn][kk] = pack2(b0, b1);
        }
        __syncthreads();
        bf16x8 af[2], bf[2];
#pragma unroll
        for (int t = 0; t < 2; t++) {
            af[t] = *(bf16x8*)&As[wm + t * 16 + fr][fk];
            bf[t] = *(bf16x8*)&Bs[wn + t * 16 + fr][fk];
        }
#pragma unroll
        for (int tm = 0; tm < 2; tm++)
#pragma unroll
            for (int tn = 0; tn < 2; tn++)
                acc[tm][tn] = __builtin_amdgcn_mfma_f32_16x16x32_bf16(af[tm], bf[tn], acc[tm][tn], 0, 0, 0);
    }
    int quad = (lane >> 4) << 2;
#pragma unroll
    for (int tm = 0; tm < 2; tm++)
#pragma unroll
        for (int r = 0; r < 4; r++) {
            int row = wm + tm * 16 + quad + r;
            if (row < mcnt) {
                int mrow = m0 + row;
                int tok = GATHERED ? at[mrow] : mrow;
                float w = GATHERED ? aw[mrow] : 1.f;
#pragma unroll
                for (int tn = 0; tn < 2; tn++)
                    atomicAdd(&out[(size_t)tok * DMODEL + n0 + wn + tn * 16 + fr],
                              w * acc[tm][tn][r]);
            }
        }
}

extern "C" void kernel_launch(void* const* d_in, const int* in_sizes, int n_in,
                              void* d_out, int out_size, void* d_ws, size_t ws_size,
                              hipStream_t stream) {
    (void)in_sizes; (void)n_in; (void)ws_size;
    const float* x  = (const float*)d_in[0];
    const float* rw = (const float*)d_in[1];
    const float* wg = (const float*)d_in[2];
    const float* wu = (const float*)d_in[3];
    const float* wd = (const float*)d_in[4];
    const float* sg = (const float*)d_in[5];
    const float* su = (const float*)d_in[6];
    const float* sd = (const float*)d_in[7];
    float* out = (float*)d_out;

    int* counts  = (int*)d_ws;           // 8
    int* offsets = counts + 8;           // 8
    int* cursors = counts + 16;          // 8
    int* ntiles  = counts + 24;          // 1 (+7 pad)
    int* tile_e  = counts + 32;          // 144
    int* tile_r  = tile_e + 144;         // 144
    int* topi    = tile_r + 144;         // 8192
    float* topw  = (float*)(topi + 8192);    // 8192
    int* at      = (int*)(topw + 8192);      // 8192
    float* aw    = (float*)(at + 8192);      // 8192
    unsigned short* h_r =
        (unsigned short*)(((uintptr_t)(aw + 8192) + 255) & ~(uintptr_t)255);
    unsigned short* h_s = h_r + (size_t)8192 * HR;   // total ws ~46.3 MB

    hipMemsetAsync(counts, 0, 32, stream);
    hipMemsetAsync(out, 0, (size_t)out_size * sizeof(float), stream);

    k_router<<<dim3(NTOK / 4), 256, 0, stream>>>(x, rw, topi, topw, counts);
    k_scan<<<1, 64, 0, stream>>>(counts, offsets, cursors, ntiles, tile_e, tile_r);
    k_fill<<<dim3(NTOK / 256), 256, 0, stream>>>(topi, topw, cursors, at, aw);

    // routed gate/up -> h_r [8192, 1408] bf16
    k_gateup<true><<<dim3(MAXTILES, HR / 64), 256, 0, stream>>>(
        x, wg, wu, HR, tile_e, tile_r, offsets, counts, ntiles, at, h_r);
    // shared gate/up -> h_s [4096, 2816] bf16
    k_gateup<false><<<dim3(NTOK / 64, HSHARED / 64), 256, 0, stream>>>(
        x, sg, su, HSHARED, nullptr, nullptr, nullptr, nullptr, nullptr, nullptr, h_s);
    // routed down -> out (weighted atomic add)
    k_down<true><<<dim3(MAXTILES, DMODEL / 64), 256, 0, stream>>>(
        h_r, wd, HR, tile_e, tile_r, offsets, counts, ntiles, at, aw, out);
    // shared down -> out
    k_down<false><<<dim3(NTOK / 64, DMODEL / 64), 256, 0, stream>>>(
        h_s, sd, HSHARED, nullptr, nullptr, nullptr, nullptr, nullptr, nullptr, nullptr, out);
}

// Round 2
// 965.771 us; speedup vs baseline: 1.9357x; 1.9357x over previous
//
#include <hip/hip_runtime.h>
#include <hip/hip_bf16.h>
#include <cstdint>

#define NTOK 4096
#define DMODEL 2048
#define NEXP 8
#define HR 1408
#define HSHARED 2816
#define MAXT64 136    // 64-row tiles (fallback)
#define MAXT128 72    // 128-row tiles (fast)

typedef __attribute__((ext_vector_type(8))) short bf16x8;
typedef __attribute__((ext_vector_type(4))) float f32x4;

__device__ inline unsigned short f2b(float f) {
    unsigned u = __float_as_uint(f);
    u += 0x7fffu + ((u >> 16) & 1u);   // RNE
    return (unsigned short)(u >> 16);
}
__device__ inline unsigned pack2(float a, float b) {
    return (unsigned)f2b(a) | ((unsigned)f2b(b) << 16);
}

// async global->LDS, 16B per lane; lds must be wave-uniform, dest = lds + lane*16
__device__ __forceinline__ void gll16(unsigned short* lds, const unsigned short* g) {
    __builtin_amdgcn_global_load_lds(
        (__attribute__((address_space(1))) void*)g,
        (__attribute__((address_space(3))) void*)lds, 16, 0, 0);
}

// ---------------- Router: logits -> softmax -> top2 -> counts ----------------
__global__ __launch_bounds__(256) void k_router(const float* __restrict__ x,
                                                const float* __restrict__ rw,
                                                int* __restrict__ topi,
                                                float* __restrict__ topw,
                                                int* __restrict__ counts) {
    int gw = (blockIdx.x * 256 + threadIdx.x) >> 6;
    int lane = threadIdx.x & 63;
    if (gw >= NTOK) return;
    const float* xr = x + (size_t)gw * DMODEL;
    float s[NEXP] = {0.f,0.f,0.f,0.f,0.f,0.f,0.f,0.f};
    for (int d = lane; d < DMODEL; d += 64) {
        float xv = xr[d];
#pragma unroll
        for (int e = 0; e < NEXP; e++) s[e] = fmaf(xv, rw[e * DMODEL + d], s[e]);
    }
#pragma unroll
    for (int e = 0; e < NEXP; e++)
        for (int o = 32; o > 0; o >>= 1) s[e] += __shfl_xor(s[e], o, 64);
    if (lane == 0) {
        int i1 = 0;
#pragma unroll
        for (int e = 1; e < NEXP; e++) if (s[e] > s[i1]) i1 = e;
        int i2 = (i1 == 0) ? 1 : 0;
#pragma unroll
        for (int e = 0; e < NEXP; e++) if (e != i1 && s[e] > s[i2]) i2 = e;
        float mx = s[0];
#pragma unroll
        for (int e = 1; e < NEXP; e++) mx = fmaxf(mx, s[e]);
        float den = 0.f, ex[NEXP];
#pragma unroll
        for (int e = 0; e < NEXP; e++) { ex[e] = __expf(s[e] - mx); den += ex[e]; }
        float v1 = ex[i1] / den, v2 = ex[i2] / den;
        float inv = 1.f / (v1 + v2 + 1e-20f);
        topi[2 * gw] = i1; topi[2 * gw + 1] = i2;
        topw[2 * gw] = v1 * inv; topw[2 * gw + 1] = v2 * inv;
        atomicAdd(&counts[i1], 1); atomicAdd(&counts[i2], 1);
    }
}

__global__ void k_scan(int* counts, int* offsets, int* cursors, int* ntiles,
                       int* tile_e, int* tile_r, int step) {
    if (threadIdx.x == 0 && blockIdx.x == 0) {
        int off = 0, nt = 0;
        for (int e = 0; e < NEXP; e++) {
            offsets[e] = off; cursors[e] = off;
            int c = counts[e];
            for (int r = 0; r < c; r += step) { tile_e[nt] = e; tile_r[nt] = r; nt++; }
            off += c;
        }
        ntiles[0] = nt;
    }
}

__global__ __launch_bounds__(256) void k_fill(const int* __restrict__ topi,
                                              const float* __restrict__ topw,
                                              int* cursors, int* at, float* aw) {
    int t = blockIdx.x * 256 + threadIdx.x;
    if (t >= NTOK) return;
#pragma unroll
    for (int k = 0; k < 2; k++) {
        int e = topi[2 * t + k];
        int pos = atomicAdd(&cursors[e], 1);
        at[pos] = t; aw[pos] = topw[2 * t + k];
    }
}

// ---------------- fp32 -> bf16 straight convert (x) ----------------
__global__ __launch_bounds__(256) void k_cvt_x(const float* __restrict__ src,
                                               unsigned short* __restrict__ dst) {
    size_t i = ((size_t)blockIdx.x * 256 + threadIdx.x) * 8;
    float4 a = *(const float4*)(src + i);
    float4 b = *(const float4*)(src + i + 4);
    uint4 v; v.x = pack2(a.x, a.y); v.y = pack2(a.z, a.w);
    v.z = pack2(b.x, b.y); v.w = pack2(b.z, b.w);
    *(uint4*)(dst + i) = v;
}

// ---------------- fp32 [K,N] -> bf16 [N,K] transpose-convert ----------------
__global__ __launch_bounds__(256) void k_tcvt(const float* __restrict__ src,
                                              unsigned short* __restrict__ dst,
                                              int K, int N) {
    src += (size_t)blockIdx.z * K * N;
    dst += (size_t)blockIdx.z * K * N;
    int n0 = blockIdx.x * 64, k0 = blockIdx.y * 64;
    __shared__ unsigned short T[64][72];
    int t = threadIdx.x;
    int kr = t >> 4, nc = (t & 15) * 4;
#pragma unroll
    for (int i = 0; i < 4; i++) {
        int k = kr + i * 16;
        float4 v = *(const float4*)(src + (size_t)(k0 + k) * N + n0 + nc);
        T[k][nc] = f2b(v.x); T[k][nc + 1] = f2b(v.y);
        T[k][nc + 2] = f2b(v.z); T[k][nc + 3] = f2b(v.w);
    }
    __syncthreads();
    int nr = t >> 3, kc = (t & 7) * 8;
#pragma unroll
    for (int j = 0; j < 2; j++) {
        int n = nr + j * 32;
        unsigned short tmp[8];
#pragma unroll
        for (int u = 0; u < 8; u++) tmp[u] = T[kc + u][n];
        *(uint4*)(dst + (size_t)(n0 + n) * K + k0 + kc) = *(uint4*)tmp;
    }
}

// ============ FAST PATH: m97-style GEMMs, bf16 A [M,K] x B^T [N,K] ============
// XOR swizzle: logical 16B chunk (row, c) lives at phys chunk (row, c ^ (row&7)).
// Staging applies the swizzle on the per-lane GLOBAL address side of the DMA.

// ---- fused gate/up: BM=128, BN=64 (of each of g,u), BK=64 ----
template <bool GATHERED>
__global__ __launch_bounds__(256) void kf_gateup(
    const unsigned short* __restrict__ xb, const unsigned short* __restrict__ BgT,
    const unsigned short* __restrict__ BuT, int K, int Hld, int ebase,
    const int* __restrict__ tile_e, const int* __restrict__ tile_r,
    const int* __restrict__ offsets, const int* __restrict__ counts,
    const int* __restrict__ ntiles, const int* __restrict__ at,
    unsigned short* __restrict__ hout) {
    int m0, mcnt;
    const unsigned short* bgw = BgT;
    const unsigned short* buw = BuT;
    if (GATHERED) {
        if ((int)blockIdx.x >= ntiles[0]) return;
        int e = tile_e[blockIdx.x];
        if (e < ebase || e >= ebase + 4) return;
        int ro = tile_r[blockIdx.x];
        m0 = offsets[e] + ro;
        mcnt = counts[e] - ro; if (mcnt > 128) mcnt = 128;
        size_t wofs = (size_t)(e - ebase) * Hld * K;
        bgw += wofs; buw += wofs;
    } else { m0 = blockIdx.x * 128; mcnt = 128; }
    int n0 = blockIdx.y * 64;

    __shared__ __align__(16) unsigned short As[128 * 64];
    __shared__ __align__(16) unsigned short Bgs[64 * 64];
    __shared__ __align__(16) unsigned short Bus[64 * 64];

    int tid = threadIdx.x;
    int wv = tid >> 6, lane = tid & 63;
    int rbase = tid >> 3;
    int kc = (tid & 7) ^ ((tid >> 3) & 7);   // swizzled logical chunk, const over j
    const unsigned short* arp[4];
#pragma unroll
    for (int j = 0; j < 4; j++) {
        int row = j * 32 + rbase;
        int cl = row < mcnt ? row : mcnt - 1;
        int grow = GATHERED ? at[m0 + cl] : (m0 + cl);
        arp[j] = xb + (size_t)grow * K + kc * 8;
    }
    const unsigned short* bgp[2];
    const unsigned short* bup[2];
#pragma unroll
    for (int j = 0; j < 2; j++) {
        int row = j * 32 + rbase;
        bgp[j] = bgw + (size_t)(n0 + row) * K + kc * 8;
        bup[j] = buw + (size_t)(n0 + row) * K + kc * 8;
    }
    unsigned short* a_l = As + (wv << 6) * 8;
    unsigned short* g_l = Bgs + (wv << 6) * 8;
    unsigned short* u_l = Bus + (wv << 6) * 8;

    int fr = lane & 15, quad = lane >> 4, sw = fr & 7;
    int wm = (wv & 1) << 6, wn = (wv >> 1) << 5;

    f32x4 accg[4][2] = {};
    f32x4 accu[4][2] = {};

    for (int k0 = 0; k0 < K; k0 += 64) {
        __syncthreads();
#pragma unroll
        for (int j = 0; j < 4; j++) gll16(a_l + j * 2048, arp[j] + k0);
#pragma unroll
        for (int j = 0; j < 2; j++) {
            gll16(g_l + j * 2048, bgp[j] + k0);
            gll16(u_l + j * 2048, bup[j] + k0);
        }
        __syncthreads();
#pragma unroll
        for (int s = 0; s < 2; s++) {
            int off = (((s << 2) + quad) ^ sw) << 3;
            bf16x8 a[4], g[2], u[2];
#pragma unroll
            for (int tm = 0; tm < 4; tm++)
                a[tm] = *(const bf16x8*)&As[(wm + tm * 16 + fr) * 64 + off];
#pragma unroll
            for (int tn = 0; tn < 2; tn++) {
                int rb = (wn + tn * 16 + fr) * 64 + off;
                g[tn] = *(const bf16x8*)&Bgs[rb];
                u[tn] = *(const bf16x8*)&Bus[rb];
            }
#pragma unroll
            for (int tm = 0; tm < 4; tm++)
#pragma unroll
                for (int tn = 0; tn < 2; tn++) {
                    accg[tm][tn] = __builtin_amdgcn_mfma_f32_16x16x32_bf16(a[tm], g[tn], accg[tm][tn], 0, 0, 0);
                    accu[tm][tn] = __builtin_amdgcn_mfma_f32_16x16x32_bf16(a[tm], u[tn], accu[tm][tn], 0, 0, 0);
                }
        }
    }
#pragma unroll
    for (int tm = 0; tm < 4; tm++)
#pragma unroll
        for (int r = 0; r < 4; r++) {
            int row = wm + tm * 16 + (quad << 2) + r;
            if (row < mcnt) {
#pragma unroll
                for (int tn = 0; tn < 2; tn++) {
                    float gv = accg[tm][tn][r], uv = accu[tm][tn][r];
                    float hv = (gv / (1.f + __expf(-gv))) * uv;
                    hout[(size_t)(m0 + row) * Hld + n0 + wn + tn * 16 + fr] = f2b(hv);
                }
            }
        }
}

// ---- down: BM=128, BN=128, BK=64; routed => weighted atomic scatter ----
template <bool GATHERED>
__global__ __launch_bounds__(256) void kf_down(
    const unsigned short* __restrict__ h, const unsigned short* __restrict__ BT,
    int K,
    const int* __restrict__ tile_e, const int* __restrict__ tile_r,
    const int* __restrict__ offsets, const int* __restrict__ counts,
    const int* __restrict__ ntiles, const int* __restrict__ at,
    const float* __restrict__ awt, float* __restrict__ out) {
    int m0, mcnt;
    const unsigned short* bw = BT;
    if (GATHERED) {
        if ((int)blockIdx.x >= ntiles[0]) return;
        int e = tile_e[blockIdx.x], ro = tile_r[blockIdx.x];
        m0 = offsets[e] + ro;
        mcnt = counts[e] - ro; if (mcnt > 128) mcnt = 128;
        bw += (size_t)e * DMODEL * K;
    } else { m0 = blockIdx.x * 128; mcnt = 128; }
    int n0 = blockIdx.y * 128;

    __shared__ __align__(16) unsigned short As[128 * 64];
    __shared__ __align__(16) unsigned short Bs[128 * 64];

    int tid = threadIdx.x;
    int wv = tid >> 6, lane = tid & 63;
    int rbase = tid >> 3;
    int kc = (tid & 7) ^ ((tid >> 3) & 7);
    const unsigned short* arp[4];
    const unsigned short* brp[4];
#pragma unroll
    for (int j = 0; j < 4; j++) {
        int row = j * 32 + rbase;
        int cl = row < mcnt ? row : mcnt - 1;
        arp[j] = h + (size_t)(m0 + cl) * K + kc * 8;
        brp[j] = bw + (size_t)(n0 + row) * K + kc * 8;
    }
    unsigned short* a_l = As + (wv << 6) * 8;
    unsigned short* b_l = Bs + (wv << 6) * 8;

    int fr = lane & 15, quad = lane >> 4, sw = fr & 7;
    int wm = (wv & 1) << 6, wn = (wv >> 1) << 6;

    f32x4 acc[4][4] = {};

    for (int k0 = 0; k0 < K; k0 += 64) {
        __syncthreads();
#pragma unroll
        for (int j = 0; j < 4; j++) {
            gll16(a_l + j * 2048, arp[j] + k0);
            gll16(b_l + j * 2048, brp[j] + k0);
        }
        __syncthreads();
#pragma unroll
        for (int s = 0; s < 2; s++) {
            int off = (((s << 2) + quad) ^ sw) << 3;
            bf16x8 a[4], b[4];
#pragma unroll
            for (int tm = 0; tm < 4; tm++)
                a[tm] = *(const bf16x8*)&As[(wm + tm * 16 + fr) * 64 + off];
#pragma unroll
            for (int tn = 0; tn < 4; tn++)
                b[tn] = *(const bf16x8*)&Bs[(wn + tn * 16 + fr) * 64 + off];
#pragma unroll
            for (int tm = 0; tm < 4; tm++)
#pragma unroll
                for (int tn = 0; tn < 4; tn++)
                    acc[tm][tn] = __builtin_amdgcn_mfma_f32_16x16x32_bf16(a[tm], b[tn], acc[tm][tn], 0, 0, 0);
        }
    }
#pragma unroll
    for (int tm = 0; tm < 4; tm++)
#pragma unroll
        for (int r = 0; r < 4; r++) {
            int row = wm + tm * 16 + (quad << 2) + r;
            if (row < mcnt) {
                if (GATHERED) {
                    int tok = at[m0 + row];
                    float w = awt[m0 + row];
#pragma unroll
                    for (int tn = 0; tn < 4; tn++)
                        atomicAdd(&out[(size_t)tok * DMODEL + n0 + wn + tn * 16 + fr],
                                  w * acc[tm][tn][r]);
                } else {
#pragma unroll
                    for (int tn = 0; tn < 4; tn++)
                        out[(size_t)(m0 + row) * DMODEL + n0 + wn + tn * 16 + fr] =
                            acc[tm][tn][r];
                }
            }
        }
}

// ============ FALLBACK PATH (round-1, proven): fp32-source 64-tile GEMMs =====
template <bool GATHERED>
__global__ __launch_bounds__(256) void k_gateup(
    const float* __restrict__ x, const float* __restrict__ Wg,
    const float* __restrict__ Wu, int Hld,
    const int* __restrict__ tile_e, const int* __restrict__ tile_r,
    const int* __restrict__ offsets, const int* __restrict__ counts,
    const int* __restrict__ ntiles, const int* __restrict__ at,
    unsigned short* __restrict__ hout) {
    int m0, mcnt;
    const float* wgp = Wg;
    const float* wup = Wu;
    if (GATHERED) {
        if ((int)blockIdx.x >= ntiles[0]) return;
        int e = tile_e[blockIdx.x], ro = tile_r[blockIdx.x];
        m0 = offsets[e] + ro;
        mcnt = counts[e] - ro; if (mcnt > 64) mcnt = 64;
        size_t wofs = (size_t)e * DMODEL * Hld;
        wgp += wofs; wup += wofs;
    } else { m0 = blockIdx.x * 64; mcnt = 64; }
    int n0 = blockIdx.y * 64;
    __shared__ unsigned short As[64][48];
    __shared__ unsigned short Bgs[64][48];
    __shared__ unsigned short Bus[64][48];
    int tid = threadIdx.x;
    int ai = tid >> 2, ak = (tid & 3) << 3;
    int arowi = m0 + (ai < mcnt ? ai : (mcnt - 1));
    const float* arow = x + (size_t)(GATHERED ? at[arowi] : arowi) * DMODEL;
    int bn = tid >> 2, bk = (tid & 3) << 1;
    const float* bcolg = wgp + (size_t)n0 + bn;
    const float* bcolu = wup + (size_t)n0 + bn;
    int lane = tid & 63, wv = tid >> 6;
    int wm = (wv & 1) << 5, wn = (wv >> 1) << 5;
    int fr = lane & 15, fk = (lane >> 4) << 3;
    f32x4 accg[2][2] = {};
    f32x4 accu[2][2] = {};
    for (int k0 = 0; k0 < DMODEL; k0 += 32) {
        __syncthreads();
        float4 a0 = *(const float4*)(arow + k0 + ak);
        float4 a1 = *(const float4*)(arow + k0 + ak + 4);
        uint4 av; av.x = pack2(a0.x, a0.y); av.y = pack2(a0.z, a0.w);
        av.z = pack2(a1.x, a1.y); av.w = pack2(a1.z, a1.w);
        *(uint4*)&As[ai][ak] = av;
#pragma unroll
        for (int j = 0; j < 4; j++) {
            int kk = bk + (j << 3);
            size_t o0 = (size_t)(k0 + kk) * Hld;
            *(unsigned*)&Bgs[bn][kk] = pack2(bcolg[o0], bcolg[o0 + Hld]);
            *(unsigned*)&Bus[bn][kk] = pack2(bcolu[o0], bcolu[o0 + Hld]);
        }
        __syncthreads();
        bf16x8 af[2], bg[2], bu[2];
#pragma unroll
        for (int t = 0; t < 2; t++) {
            af[t] = *(bf16x8*)&As[wm + t * 16 + fr][fk];
            bg[t] = *(bf16x8*)&Bgs[wn + t * 16 + fr][fk];
            bu[t] = *(bf16x8*)&Bus[wn + t * 16 + fr][fk];
        }
#pragma unroll
        for (int tm = 0; tm < 2; tm++)
#pragma unroll
            for (int tn = 0; tn < 2; tn++) {
                accg[tm][tn] = __builtin_amdgcn_mfma_f32_16x16x32_bf16(af[tm], bg[tn], accg[tm][tn], 0, 0, 0);
                accu[tm][tn] = __builtin_amdgcn_mfma_f32_16x16x32_bf16(af[tm], bu[tn], accu[tm][tn], 0, 0, 0);
            }
    }
    int quad = (lane >> 4) << 2;
#pragma unroll
    for (int tm = 0; tm < 2; tm++)
#pragma unroll
        for (int r = 0; r < 4; r++) {
            int row = wm + tm * 16 + quad + r;
            if (row < mcnt) {
#pragma unroll
                for (int tn = 0; tn < 2; tn++) {
                    float g = accg[tm][tn][r], u = accu[tm][tn][r];
                    float hv = (g / (1.f + __expf(-g))) * u;
                    hout[(size_t)(m0 + row) * Hld + n0 + wn + tn * 16 + fr] = f2b(hv);
                }
            }
        }
}

template <bool GATHERED>
__global__ __launch_bounds__(256) void k_down(
    const unsigned short* __restrict__ h, const float* __restrict__ Wd, int Hld,
    const int* __restrict__ tile_e, const int* __restrict__ tile_r,
    const int* __restrict__ offsets, const int* __restrict__ counts,
    const int* __restrict__ ntiles, const int* __restrict__ at,
    const float* __restrict__ aw, float* __restrict__ out) {
    int m0, mcnt;
    const float* wdp = Wd;
    if (GATHERED) {
        if ((int)blockIdx.x >= ntiles[0]) return;
        int e = tile_e[blockIdx.x], ro = tile_r[blockIdx.x];
        m0 = offsets[e] + ro;
        mcnt = counts[e] - ro; if (mcnt > 64) mcnt = 64;
        wdp += (size_t)e * Hld * DMODEL;
    } else { m0 = blockIdx.x * 64; mcnt = 64; }
    int n0 = blockIdx.y * 64;
    __shared__ unsigned short As[64][48];
    __shared__ unsigned short Bs[64][48];
    int tid = threadIdx.x;
    int ai = tid >> 2, ak = (tid & 3) << 3;
    const unsigned short* arow = h + (size_t)(m0 + (ai < mcnt ? ai : (mcnt - 1))) * Hld;
    int bn = tid >> 2, bk = (tid & 3) << 1;
    const float* bcol = wdp + (size_t)n0 + bn;
    int lane = tid & 63, wv = tid >> 6;
    int wm = (wv & 1) << 5, wn = (wv >> 1) << 5;
    int fr = lane & 15, fk = (lane >> 4) << 3;
    f32x4 acc[2][2] = {};
    for (int k0 = 0; k0 < Hld; k0 += 32) {
        __syncthreads();
        *(uint4*)&As[ai][ak] = *(const uint4*)(arow + k0 + ak);
#pragma unroll
        for (int j = 0; j < 4; j++) {
            int kk = bk + (j << 3);
            size_t o0 = (size_t)(k0 + kk) * DMODEL;
            *(unsigned*)&Bs[bn][kk] = pack2(bcol[o0], bcol[o0 + DMODEL]);
        }
        __syncthreads();
        bf16x8 af[2], bf[2];
#pragma unroll
        for (int t = 0; t < 2; t++) {
            af[t] = *(bf16x8*)&As[wm + t * 16 + fr][fk];
            bf[t] = *(bf16x8*)&Bs[wn + t * 16 + fr][fk];
        }
#pragma unroll
        for (int tm = 0; tm < 2; tm++)
#pragma unroll
            for (int tn = 0; tn < 2; tn++)
                acc[tm][tn] = __builtin_amdgcn_mfma_f32_16x16x32_bf16(af[tm], bf[tn], acc[tm][tn], 0, 0, 0);
    }
    int quad = (lane >> 4) << 2;
#pragma unroll
    for (int tm = 0; tm < 2; tm++)
#pragma unroll
        for (int r = 0; r < 4; r++) {
            int row = wm + tm * 16 + quad + r;
            if (row < mcnt) {
                int mrow = m0 + row;
                int tok = GATHERED ? at[mrow] : mrow;
                float w = GATHERED ? aw[mrow] : 1.f;
#pragma unroll
                for (int tn = 0; tn < 2; tn++)
                    atomicAdd(&out[(size_t)tok * DMODEL + n0 + wn + tn * 16 + fr],
                              w * acc[tm][tn][r]);
            }
        }
}

extern "C" void kernel_launch(void* const* d_in, const int* in_sizes, int n_in,
                              void* d_out, int out_size, void* d_ws, size_t ws_size,
                              hipStream_t stream) {
    (void)in_sizes; (void)n_in;
    const float* x  = (const float*)d_in[0];
    const float* rw = (const float*)d_in[1];
    const float* wg = (const float*)d_in[2];
    const float* wu = (const float*)d_in[3];
    const float* wd = (const float*)d_in[4];
    const float* sg = (const float*)d_in[5];
    const float* su = (const float*)d_in[6];
    const float* sd = (const float*)d_in[7];
    float* out = (float*)d_out;

    // ---- shared meta layout ----
    int* counts  = (int*)d_ws;
    int* offsets = counts + 8;
    int* cursors = counts + 16;
    int* ntiles  = counts + 24;
    int* tile_e  = counts + 32;          // 144
    int* tile_r  = tile_e + 144;         // 144
    int* topi    = tile_r + 144;         // 8192
    float* topw  = (float*)(topi + 8192);
    int* at      = (int*)(topw + 8192);
    float* aw    = (float*)(at + 8192);

    const size_t META = 262144;
    const size_t XB   = (size_t)NTOK * DMODEL * 2;          // 16,777,216
    const size_t POOL_NEED = 69206016;
    const size_t FAST_NEED = META + XB + POOL_NEED;         // 86,245,376
    bool fast = ws_size >= FAST_NEED;

    hipMemsetAsync(counts, 0, 32, stream);
    k_router<<<dim3(NTOK / 4), 256, 0, stream>>>(x, rw, topi, topw, counts);
    k_scan<<<1, 64, 0, stream>>>(counts, offsets, cursors, ntiles, tile_e, tile_r,
                                 fast ? 128 : 64);
    k_fill<<<dim3(NTOK / 256), 256, 0, stream>>>(topi, topw, cursors, at, aw);

    if (fast) {
        char* base = (char*)d_ws;
        unsigned short* xb = (unsigned short*)(base + META);
        char* pool = base + META + XB;
        unsigned short* sgT = (unsigned short*)pool;                  // 11,534,336
        unsigned short* suT = (unsigned short*)(pool + 11534336);     // 11,534,336
        unsigned short* h_s = (unsigned short*)(pool + 23068672);     // 23,068,672
        unsigned short* sdT = (unsigned short*)(pool + 46137344);     // 11,534,336
        unsigned short* wgT = (unsigned short*)pool;                  // 23,068,672 (4 exp)
        unsigned short* wuT = (unsigned short*)(pool + 23068672);     // 23,068,672 (4 exp)
        unsigned short* h_r = (unsigned short*)(pool + 46137344);     // 23,068,672
        unsigned short* wdT = (unsigned short*)pool;                  // 46,137,344 (8 exp)

        k_cvt_x<<<dim3(4096), 256, 0, stream>>>(x, xb);

        // ---- shared expert ----
        k_tcvt<<<dim3(HSHARED / 64, DMODEL / 64, 1), 256, 0, stream>>>(sg, sgT, DMODEL, HSHARED);
        k_tcvt<<<dim3(HSHARED / 64, DMODEL / 64, 1), 256, 0, stream>>>(su, suT, DMODEL, HSHARED);
        kf_gateup<false><<<dim3(NTOK / 128, HSHARED / 64), 256, 0, stream>>>(
            xb, sgT, suT, DMODEL, HSHARED, 0,
            nullptr, nullptr, nullptr, nullptr, nullptr, nullptr, h_s);
        k_tcvt<<<dim3(DMODEL / 64, HSHARED / 64, 1), 256, 0, stream>>>(sd, sdT, HSHARED, DMODEL);
        kf_down<false><<<dim3(NTOK / 128, DMODEL / 128), 256, 0, stream>>>(
            h_s, sdT, HSHARED,
            nullptr, nullptr, nullptr, nullptr, nullptr, nullptr, nullptr, out);

        // ---- routed experts, two 4-expert groups ----
        k_tcvt<<<dim3(HR / 64, DMODEL / 64, 4), 256, 0, stream>>>(wg, wgT, DMODEL, HR);
        k_tcvt<<<dim3(HR / 64, DMODEL / 64, 4), 256, 0, stream>>>(wu, wuT, DMODEL, HR);
        kf_gateup<true><<<dim3(MAXT128, HR / 64), 256, 0, stream>>>(
            xb, wgT, wuT, DMODEL, HR, 0,
            tile_e, tile_r, offsets, counts, ntiles, at, h_r);
        k_tcvt<<<dim3(HR / 64, DMODEL / 64, 4), 256, 0, stream>>>(
            wg + (size_t)4 * DMODEL * HR, wgT, DMODEL, HR);
        k_tcvt<<<dim3(HR / 64, DMODEL / 64, 4), 256, 0, stream>>>(
            wu + (size_t)4 * DMODEL * HR, wuT, DMODEL, HR);
        kf_gateup<true><<<dim3(MAXT128, HR / 64), 256, 0, stream>>>(
            xb, wgT, wuT, DMODEL, HR, 4,
            tile_e, tile_r, offsets, counts, ntiles, at, h_r);
        k_tcvt<<<dim3(DMODEL / 64, HR / 64, 8), 256, 0, stream>>>(wd, wdT, HR, DMODEL);
        kf_down<true><<<dim3(MAXT128, DMODEL / 128), 256, 0, stream>>>(
            h_r, wdT, HR,
            tile_e, tile_r, offsets, counts, ntiles, at, aw, out);
    } else {
        // round-1 proven path
        unsigned short* h_r =
            (unsigned short*)(((uintptr_t)(aw + 8192) + 255) & ~(uintptr_t)255);
        unsigned short* h_s = h_r + (size_t)8192 * HR;
        hipMemsetAsync(out, 0, (size_t)out_size * sizeof(float), stream);
        k_gateup<true><<<dim3(MAXT64, HR / 64), 256, 0, stream>>>(
            x, wg, wu, HR, tile_e, tile_r, offsets, counts, ntiles, at, h_r);
        k_gateup<false><<<dim3(NTOK / 64, HSHARED / 64), 256, 0, stream>>>(
            x, sg, su, HSHARED, nullptr, nullptr, nullptr, nullptr, nullptr, nullptr, h_s);
        k_down<true><<<dim3(MAXT64, DMODEL / 64), 256, 0, stream>>>(
            h_r, wd, HR, tile_e, tile_r, offsets, counts, ntiles, at, aw, out);
        k_down<false><<<dim3(NTOK / 64, DMODEL / 64), 256, 0, stream>>>(
            h_s, sd, HSHARED, nullptr, nullptr, nullptr, nullptr, nullptr, nullptr, nullptr, out);
    }
}